// Round 1
// baseline (1500.591 us; speedup 1.0000x reference)
//
#include <hip/hip_runtime.h>
#include <stdint.h>

typedef unsigned int u32;
typedef unsigned long long u64;

#define HH 64
#define WW 96
#define HW 6144
#define CC 512
#define NANCH 55296
#define PRE 6000
#define POST 300
#define CAP 8192

// 9 base anchors (STRIDE=16, scales 8/16/32, ratios .5/1/2), center is always (x*16+8, y*16+8).
__device__ __constant__ float c_aw[9] = {184.f,368.f,736.f,128.f,256.f,512.f,88.f,176.f,352.f};
__device__ __constant__ float c_ah[9] = {96.f,192.f,384.f,128.f,256.f,512.f,176.f,352.f,704.f};

// ---------------- K1: 3x3 conv 512->512 + bias + relu ----------------
// grid (64 rows, 8 oc-groups), block 256. Tile: 1 row (96 pos) x 64 oc.
// thread (pt=tid&15 -> 6 contiguous positions, ot=tid>>4 -> ocs ot+16k).
__global__ __launch_bounds__(256) void k_conv3(
    const float* __restrict__ X, const float* __restrict__ Wt,
    const float* __restrict__ Bc, float* __restrict__ Y)
{
  __shared__ float Xs[2400];   // 8 ic x 3 rows x 100 (rows padded: idx x+1, x in [-1,96])
  __shared__ float Ws[4608];   // (ic*9+tap)*64 + oc_l
  const int tid = threadIdx.x;
  const int y0  = blockIdx.x;
  const int oc0 = blockIdx.y * 64;
  const int pt  = tid & 15;
  const int ot  = tid >> 4;
  const int xs  = pt * 6;

  float accM[6][4], accC[6][4];
  #pragma unroll
  for (int p = 0; p < 6; ++p)
    #pragma unroll
    for (int k = 0; k < 4; ++k){ accM[p][k] = 0.f; accC[p][k] = 0.f; }

  for (int c0 = 0; c0 < CC; c0 += 8){
    __syncthreads();
    for (int i = tid; i < 2352; i += 256){          // 8 ic * 3 rows * 98
      int ic  = i / 294;
      int rem = i - ic * 294;
      int r   = rem / 98;
      int xx  = rem - r * 98 - 1;
      int row = y0 - 1 + r;
      float v = 0.f;
      if ((unsigned)row < 64u && (unsigned)xx < 96u)
        v = X[(c0 + ic) * HW + row * WW + xx];
      Xs[ic * 300 + r * 100 + xx + 1] = v;
    }
    for (int i = tid; i < 4608; i += 256){          // 64 oc * (8 ic * 9 taps)
      int oc = i / 72;
      int k  = i - oc * 72;
      Ws[k * 64 + oc] = Wt[(oc0 + oc) * 4608 + c0 * 9 + k];
    }
    __syncthreads();
    #pragma unroll
    for (int ic = 0; ic < 8; ++ic){
      #pragma unroll
      for (int dy = 0; dy < 3; ++dy){
        float xv[8];
        const float2* xp = reinterpret_cast<const float2*>(Xs + ic*300 + dy*100 + xs);
        float2 a0 = xp[0], a1 = xp[1], a2 = xp[2], a3 = xp[3];
        xv[0]=a0.x; xv[1]=a0.y; xv[2]=a1.x; xv[3]=a1.y;
        xv[4]=a2.x; xv[5]=a2.y; xv[6]=a3.x; xv[7]=a3.y;
        #pragma unroll
        for (int dx = 0; dx < 3; ++dx){
          const float* wr = Ws + (ic*9 + dy*3 + dx)*64 + ot;
          float w0 = wr[0], w1 = wr[16], w2 = wr[32], w3 = wr[48];
          #pragma unroll
          for (int p = 0; p < 6; ++p){
            float v = xv[p + dx];
            accC[p][0] += v * w0;
            accC[p][1] += v * w1;
            accC[p][2] += v * w2;
            accC[p][3] += v * w3;
          }
        }
      }
    }
    // two-level accumulation: keeps fp32 rounding error ~30x below a flat
    // 4608-term sequential sum (score-ranking must match numpy reference).
    #pragma unroll
    for (int p = 0; p < 6; ++p)
      #pragma unroll
      for (int k = 0; k < 4; ++k){ accM[p][k] += accC[p][k]; accC[p][k] = 0.f; }
  }
  #pragma unroll
  for (int k = 0; k < 4; ++k){
    int oc = oc0 + k*16 + ot;
    float b = Bc[oc];
    float v0 = fmaxf(accM[0][k] + b, 0.f);
    float v1 = fmaxf(accM[1][k] + b, 0.f);
    float v2 = fmaxf(accM[2][k] + b, 0.f);
    float v3 = fmaxf(accM[3][k] + b, 0.f);
    float v4 = fmaxf(accM[4][k] + b, 0.f);
    float v5 = fmaxf(accM[5][k] + b, 0.f);
    float2* yp = reinterpret_cast<float2*>(Y + oc*HW + y0*WW + xs);
    yp[0] = make_float2(v0, v1);
    yp[1] = make_float2(v2, v3);
    yp[2] = make_float2(v4, v5);
  }
}

// ---------------- K2: 1x1 heads + softmax + box decode ----------------
// grid 96 blocks x 64 positions; 54 outputs (18 cls + 36 bbox) padded to 64.
__global__ __launch_bounds__(256) void k_head(
    const float* __restrict__ Y, const float* __restrict__ cw,
    const float* __restrict__ cb, const float* __restrict__ bw,
    const float* __restrict__ bb, const float* __restrict__ info,
    float* __restrict__ scores, float4* __restrict__ boxes)
{
  __shared__ float Ys[4096];   // [c][pos] then reused as logits [pos][out]
  __shared__ float Wsh[4096];  // [c][out]
  const int tid = threadIdx.x;
  const int p0  = blockIdx.x * 64;
  const int po  = tid & 15;    // 4 contiguous positions
  const int oj  = tid >> 4;    // outputs oj+16k
  float accM[4][4], accC[4][4];
  #pragma unroll
  for (int p = 0; p < 4; ++p)
    #pragma unroll
    for (int k = 0; k < 4; ++k){ accM[p][k] = 0.f; accC[p][k] = 0.f; }

  for (int c0 = 0; c0 < CC; c0 += 64){
    __syncthreads();
    for (int i = tid; i < 4096; i += 256){
      int c = i >> 6, p = i & 63;
      Ys[i] = Y[(c0 + c) * HW + p0 + p];
    }
    for (int i = tid; i < 4096; i += 256){
      int c = i >> 6, o = i & 63;
      int gc = c0 + c;
      float v = 0.f;
      if (o < 18) v = cw[o * 512 + gc];
      else if (o < 54) v = bw[(o - 18) * 512 + gc];
      Wsh[i] = v;
    }
    __syncthreads();
    for (int c = 0; c < 64; ++c){
      const float4 xv = *reinterpret_cast<const float4*>(Ys + c*64 + po*4);
      float xa[4] = {xv.x, xv.y, xv.z, xv.w};
      const float* wr = Wsh + c*64 + oj;
      float wv[4] = {wr[0], wr[16], wr[32], wr[48]};
      #pragma unroll
      for (int p = 0; p < 4; ++p)
        #pragma unroll
        for (int k = 0; k < 4; ++k)
          accC[p][k] += xa[p] * wv[k];
    }
    #pragma unroll
    for (int p = 0; p < 4; ++p)
      #pragma unroll
      for (int k = 0; k < 4; ++k){ accM[p][k] += accC[p][k]; accC[p][k] = 0.f; }
  }
  __syncthreads();
  #pragma unroll
  for (int p = 0; p < 4; ++p)
    #pragma unroll
    for (int k = 0; k < 4; ++k){
      int o = oj + 16*k;
      float bias = (o < 18) ? cb[o] : ((o < 54) ? bb[o - 18] : 0.f);
      Ys[(po*4 + p)*64 + o] = accM[p][k] + bias;
    }
  __syncthreads();
  float imH = info[0], imW = info[1], imS = info[2];
  for (int it = tid; it < 576; it += 256){
    int pl = it / 9;
    int a  = it - pl*9;
    const float* L = Ys + pl*64;
    float l0 = L[a], l1 = L[9 + a];
    float mx = fmaxf(l0, l1);
    float e0 = expf(l0 - mx), e1 = expf(l1 - mx);
    float sc = e1 / (e0 + e1);                      // softmax fg prob, jax order
    float d0 = L[18 + a*4 + 0], d1 = L[18 + a*4 + 1];
    float d2 = L[18 + a*4 + 2], d3 = L[18 + a*4 + 3];
    int pos = p0 + pl;
    int yy = pos / 96;
    int xx = pos - yy * 96;
    float aw = c_aw[a], ah = c_ah[a];
    float acx = (float)(xx * 16 + 8);
    float acy = (float)(yy * 16 + 8);
    // _rn intrinsics: forbid fma-contraction so coords match numpy op-for-op
    float cx = __fadd_rn(__fmul_rn(d0, aw), acx);
    float cy = __fadd_rn(__fmul_rn(d1, ah), acy);
    float pw = __fmul_rn(expf(d2), aw);
    float ph = __fmul_rn(expf(d3), ah);
    float hx = __fmul_rn(0.5f, pw);
    float hy = __fmul_rn(0.5f, ph);
    float x1 = fminf(fmaxf(__fadd_rn(cx, -hx), 0.f), imW - 1.f);
    float y1 = fminf(fmaxf(__fadd_rn(cy, -hy), 0.f), imH - 1.f);
    float x2 = fminf(fmaxf(__fadd_rn(cx,  hx), 0.f), imW - 1.f);
    float y2 = fminf(fmaxf(__fadd_rn(cy,  hy), 0.f), imH - 1.f);
    float ms = 16.f * imS;
    bool keep = ((x2 - x1 + 1.f) >= ms) && ((y2 - y1 + 1.f) >= ms);
    int g = pos * 9 + a;
    scores[g] = keep ? sc : -__builtin_inff();
    boxes[g]  = make_float4(x1, y1, x2, y2);
  }
}

// ---------------- top-6000 selection ----------------
__device__ __forceinline__ u32 sortkey(float s){
  u32 u = __float_as_uint(s);
  return u ^ ((u & 0x80000000u) ? 0xFFFFFFFFu : 0x80000000u);
}

__global__ __launch_bounds__(256) void k_hist(const float* __restrict__ scores, u32* __restrict__ hist){
  int i = blockIdx.x * 256 + threadIdx.x;
  if (i >= NANCH) return;
  atomicAdd(&hist[sortkey(scores[i]) >> 16], 1u);
}

__global__ __launch_bounds__(1024) void k_thresh1(const u32* __restrict__ hist, u32* __restrict__ ctr){
  __shared__ u32 cs[1024];
  int t = threadIdx.x;
  int b0 = t * 64;
  u32 s = 0;
  for (int i = 0; i < 64; ++i) s += hist[b0 + i];
  cs[t] = s;
  __syncthreads();
  for (int off = 1; off < 1024; off <<= 1){
    u32 v = cs[t];
    u32 ad = (t + off < 1024) ? cs[t + off] : 0u;
    __syncthreads();
    cs[t] = v + ad;
    __syncthreads();
  }
  u32 here  = cs[t];
  u32 after = (t < 1023) ? cs[t + 1] : 0u;
  if (here >= 6000u && after < 6000u){
    u32 acc = after;
    for (int b = b0 + 63; b >= b0; --b){
      u32 h = hist[b];
      acc += h;
      if (acc >= 6000u){ ctr[1] = (u32)b; ctr[2] = acc - h; break; }
    }
  }
  if (t == 0 && cs[0] < 6000u){ ctr[1] = 0u; ctr[2] = 0u; }
}

__global__ __launch_bounds__(256) void k_hist2(const float* __restrict__ scores,
                                               const u32* __restrict__ ctr, u32* __restrict__ hist2){
  int i = blockIdx.x * 256 + threadIdx.x;
  if (i >= NANCH) return;
  u32 key = sortkey(scores[i]);
  if ((key >> 16) == ctr[1]) atomicAdd(&hist2[key & 0xFFFFu], 1u);
}

__global__ __launch_bounds__(1024) void k_thresh2(const u32* __restrict__ hist2, u32* __restrict__ ctr){
  __shared__ u32 cs[1024];
  int t = threadIdx.x;
  u32 above  = ctr[2];
  u32 target = 6000u - above;
  int b0 = t * 64;
  u32 s = 0;
  for (int i = 0; i < 64; ++i) s += hist2[b0 + i];
  cs[t] = s;
  __syncthreads();
  for (int off = 1; off < 1024; off <<= 1){
    u32 v = cs[t];
    u32 ad = (t + off < 1024) ? cs[t + off] : 0u;
    __syncthreads();
    cs[t] = v + ad;
    __syncthreads();
  }
  u32 here  = cs[t];
  u32 after = (t < 1023) ? cs[t + 1] : 0u;
  if (here >= target && after < target){
    u32 acc = after;
    for (int b = b0 + 63; b >= b0; --b){
      u32 h = hist2[b];
      acc += h;
      if (acc >= target){ ctr[3] = (ctr[1] << 16) | (u32)b; break; }
    }
  }
  if (t == 0 && cs[0] < target) ctr[3] = (ctr[1] << 16);
}

__global__ __launch_bounds__(256) void k_compact(const float* __restrict__ scores,
                                                 u32* __restrict__ ctr, u64* __restrict__ keys){
  int i = blockIdx.x * 256 + threadIdx.x;
  if (i >= NANCH) return;
  u32 key = sortkey(scores[i]);
  if (key >= ctr[3]){
    u32 pos = atomicAdd(&ctr[0], 1u);
    if (pos < CAP) keys[pos] = ((u64)key << 32) | (u64)(u32)(~(u32)i);  // ~i: ties -> lower index first
  }
}

// single-block bitonic sort of 8192 u64 keys (desc), then gather top-6000 boxes+areas
__global__ __launch_bounds__(1024) void k_sort(const u64* __restrict__ keys, const u32* __restrict__ ctr,
                                               const float4* __restrict__ boxes,
                                               float4* __restrict__ topB, float* __restrict__ topA){
  __shared__ u64 sk[CAP];   // 64 KB
  int t = threadIdx.x;
  u32 count = ctr[0]; if (count > CAP) count = CAP;
  for (int i = t; i < CAP; i += 1024)
    sk[i] = (i < (int)count) ? keys[i] : 0ull;
  __syncthreads();
  for (int k = 2; k <= CAP; k <<= 1){
    for (int j = k >> 1; j > 0; j >>= 1){
      for (int i = t; i < CAP; i += 1024){
        int l = i ^ j;
        if (l > i){
          u64 a = sk[i], b2 = sk[l];
          bool sw = ((i & k) == 0) ? (a < b2) : (a > b2);   // descending
          if (sw){ sk[i] = b2; sk[l] = a; }
        }
      }
      __syncthreads();
    }
  }
  for (int r = t; r < PRE; r += 1024){
    u64 key = sk[r];
    float4 bv = make_float4(0.f, 0.f, 0.f, 0.f);
    float area = 1.f;
    if (r < (int)count && (key >> 32) != 0ull){
      u32 idx = ~(u32)key;
      if (idx < NANCH){
        bv = boxes[idx];
        area = (bv.z - bv.x + 1.f) * (bv.w - bv.y + 1.f);
      }
    }
    topB[r] = bv;
    topA[r] = area;
  }
}

// ---------------- K7: sequential greedy NMS, single block ----------------
__global__ __launch_bounds__(1024) void k_nms(const float4* __restrict__ topB, const float* __restrict__ topA,
                                              const u32* __restrict__ ctr, float* __restrict__ out){
  __shared__ u32 mask[192];     // 6144 suppression bits
  __shared__ int sel;
  __shared__ int kept[POST];
  const int t = threadIdx.x;
  int validN = (int)ctr[0]; if (validN > PRE) validN = PRE;
  for (int w = t; w < 192; w += 1024) mask[w] = 0u;
  __syncthreads();
  for (int j = validN + t; j < 6144; j += 1024) atomicOr(&mask[j >> 5], 1u << (j & 31));
  float4 bx[6]; float ar[6];
  #pragma unroll
  for (int m = 0; m < 6; ++m){
    int j = t + m * 1024;
    if (j < PRE){ bx[m] = topB[j]; ar[m] = topA[j]; }
    else { bx[m] = make_float4(0.f,0.f,0.f,0.f); ar[m] = 1.f; }
  }
  __syncthreads();
  int p = 0;  // thread-0 pointer (boxes sorted by score desc -> argmax == first free bit)
  for (int k = 0; k < POST; ++k){
    if (t == 0){
      int i = -1;
      for (int w = p >> 5; w < 192; ++w){
        u32 m = ~mask[w];
        if (m){ i = (w << 5) + __ffs(m) - 1; break; }
      }
      sel = i;
      kept[k] = i;
      if (i >= 0) p = i;
    }
    __syncthreads();
    int i = sel;
    if (i >= 0){
      float4 bi = topB[i];
      float ai = topA[i];
      #pragma unroll
      for (int m = 0; m < 6; ++m){
        int j = t + m * 1024;
        if (j < PRE){
          float xx1 = fmaxf(bi.x, bx[m].x);
          float yy1 = fmaxf(bi.y, bx[m].y);
          float xx2 = fminf(bi.z, bx[m].z);
          float yy2 = fminf(bi.w, bx[m].w);
          float iw = fmaxf(xx2 - xx1 + 1.f, 0.f);
          float ih = fmaxf(yy2 - yy1 + 1.f, 0.f);
          float inter = iw * ih;
          float iou = inter / (ai + ar[m] - inter);
          if (iou > 0.7f) atomicOr(&mask[j >> 5], 1u << (j & 31));  // self j==i: iou=1 -> advances ptr
        }
      }
    }
    __syncthreads();
  }
  for (int q = t; q < 1500; q += 1024){
    int r = q / 5;
    int c = q - r * 5;
    int i = kept[r];
    float v = 0.f;
    if (i >= 0 && c > 0){
      float4 b = topB[i];
      v = (c == 1) ? b.x : (c == 2) ? b.y : (c == 3) ? b.z : b.w;
    }
    out[q] = v;
  }
}

// ---------------- launch ----------------
extern "C" void kernel_launch(void* const* d_in, const int* in_sizes, int n_in,
                              void* d_out, int out_size, void* d_ws, size_t ws_size,
                              hipStream_t stream)
{
  const float* fm   = (const float*)d_in[0];
  const float* info = (const float*)d_in[1];
  const float* cw3  = (const float*)d_in[2];
  const float* cb3  = (const float*)d_in[3];
  const float* clw  = (const float*)d_in[4];
  const float* clb  = (const float*)d_in[5];
  const float* bbw  = (const float*)d_in[6];
  const float* bbb  = (const float*)d_in[7];
  float* out = (float*)d_out;

  char* base = (char*)d_ws;
  u32*   hist   = (u32*)  (base + 0);          // 65536 u32
  u32*   hist2  = (u32*)  (base + 262144);     // 65536 u32
  u32*   ctr    = (u32*)  (base + 524288);     // [0]=count [1]=T16 [2]=above [3]=K32
  float* Y      = (float*)(base + 524544);     // 512*6144 f32 = 12.58 MB
  float* scores = (float*)(base + 13107456);   // 55296 f32
  float4* boxes = (float4*)(base + 13328640);  // 55296 f32x4
  u64*   keys   = (u64*)  (base + 14213376);   // 8192 u64
  float4* topB  = (float4*)(base + 14278912);  // 6016 f32x4
  float* topA   = (float*)(base + 14375168);   // 6016 f32
  // total ws use: 14399232 B (~14.4 MB)

  hipMemsetAsync(base, 0, 524544, stream);     // hist, hist2, ctr
  k_conv3  <<<dim3(64, 8), 256, 0, stream>>>(fm, cw3, cb3, Y);
  k_head   <<<96,  256, 0, stream>>>(Y, clw, clb, bbw, bbb, info, scores, boxes);
  k_hist   <<<216, 256, 0, stream>>>(scores, hist);
  k_thresh1<<<1,  1024, 0, stream>>>(hist, ctr);
  k_hist2  <<<216, 256, 0, stream>>>(scores, ctr, hist2);
  k_thresh2<<<1,  1024, 0, stream>>>(hist2, ctr);
  k_compact<<<216, 256, 0, stream>>>(scores, ctr, keys);
  k_sort   <<<1,  1024, 0, stream>>>(keys, ctr, boxes, topB, topA);
  k_nms    <<<1,  1024, 0, stream>>>(topB, topA, ctr, out);
}

// Round 2
// 1305.315 us; speedup vs baseline: 1.1496x; 1.1496x over previous
//
#include <hip/hip_runtime.h>
#include <stdint.h>

typedef unsigned int u32;
typedef unsigned long long u64;

#define HH 64
#define WW 96
#define HW 6144
#define CC 512
#define NANCH 55296
#define PRE 6000
#define POST 300
#define CAP 8192

// 9 base anchors (STRIDE=16, scales 8/16/32, ratios .5/1/2), center always (x*16+8, y*16+8).
__device__ __constant__ float c_aw[9] = {184.f,368.f,736.f,128.f,256.f,512.f,88.f,176.f,352.f};
__device__ __constant__ float c_ah[9] = {96.f,192.f,384.f,128.f,256.f,512.f,176.f,352.f,704.f};

// ---------------- K1: 3x3 conv 512->512 + bias + relu ----------------
// grid (64 rows, 8 oc-groups), block 256. Tile: 1 row (96 pos) x 64 oc.
// Ws layout [oc][72]: linear staging write (was 32-way bank conflict in R1),
// inner-loop weight reads = 4 distinct banks + broadcast (72 mod 32 = 8).
// Xs layout [ic][3][104], data at cell x+4 (f4-aligned), pads at cells 3/100.
// Global loads for chunk c+1 issued before compute of chunk c (latency hiding).
__global__ __launch_bounds__(256) void k_conv3(
    const float* __restrict__ X, const float* __restrict__ Wt,
    const float* __restrict__ Bc, float* __restrict__ Y)
{
  __shared__ float Xs[8*312];   // 9.75 KB
  __shared__ float Ws[4608];    // 18 KB
  const int tid = threadIdx.x;
  const int y0  = blockIdx.x;
  const int oc0 = blockIdx.y * 64;
  const int pt  = tid & 15;
  const int ot  = tid >> 4;
  const int xs  = pt * 6;

  // zero the 48 pad cells once (cells 3 and 100 of each of 24 rows); persist across chunks
  if (tid < 48){
    int ic = tid / 6, j = tid - ic*6, r = j >> 1;
    Xs[ic*312 + r*104 + ((j & 1) ? 100 : 3)] = 0.f;
  }

  float accM[6][4], accC[6][4];
  #pragma unroll
  for (int p = 0; p < 6; ++p)
    #pragma unroll
    for (int k = 0; k < 4; ++k){ accM[p][k] = 0.f; accC[p][k] = 0.f; }

  float4 xr[3], wr[5];

  // X: 576 f4 items (8 ic x 3 rows x 24 f4); W: 1152 f4 items (64 oc x 18 f4)
  auto loadX = [&](int c0){
    #pragma unroll
    for (int n = 0; n < 3; ++n){
      int i = tid + 256*n;
      float4 v = make_float4(0.f,0.f,0.f,0.f);
      if (i < 576){
        int ic = i / 72, rem = i - ic*72;
        int r = rem / 24, x4 = rem - r*24;
        int row = y0 - 1 + r;
        if ((unsigned)row < 64u)
          v = *reinterpret_cast<const float4*>(X + (c0+ic)*HW + row*WW + x4*4);
      }
      xr[n] = v;
    }
  };
  auto loadW = [&](int c0){
    #pragma unroll
    for (int n = 0; n < 5; ++n){
      int i = tid + 256*n;
      if (i < 1152){
        int oc = i / 18, k4 = i - oc*18;
        wr[n] = *reinterpret_cast<const float4*>(Wt + (oc0+oc)*4608 + c0*9 + k4*4);
      }
    }
  };
  auto storeXW = [&](){
    #pragma unroll
    for (int n = 0; n < 3; ++n){
      int i = tid + 256*n;
      if (i < 576){
        int ic = i / 72, rem = i - ic*72;
        int r = rem / 24, x4 = rem - r*24;
        *reinterpret_cast<float4*>(Xs + ic*312 + r*104 + 4 + x4*4) = xr[n];
      }
    }
    #pragma unroll
    for (int n = 0; n < 5; ++n){
      int i = tid + 256*n;
      if (i < 1152){
        int oc = i / 18, k4 = i - oc*18;
        *reinterpret_cast<float4*>(Ws + oc*72 + k4*4) = wr[n];
      }
    }
  };

  loadX(0); loadW(0);
  for (int ch = 0; ch < 64; ++ch){
    __syncthreads();               // previous compute done reading LDS
    storeXW();
    __syncthreads();               // LDS ready
    if (ch < 63){ loadX((ch+1)*8); loadW((ch+1)*8); }   // in flight during compute
    #pragma unroll
    for (int ic = 0; ic < 8; ++ic){
      #pragma unroll
      for (int dy = 0; dy < 3; ++dy){
        // aligned b64 window: cells xs+2 .. xs+11  (x = xs-2 .. xs+9); xv[1+p+dx] = x(xs-1+p+dx)
        const float2* xp = reinterpret_cast<const float2*>(Xs + ic*312 + dy*104 + 2 + xs);
        float2 a0 = xp[0], a1 = xp[1], a2 = xp[2], a3 = xp[3], a4 = xp[4];
        float xv[10] = {a0.x,a0.y,a1.x,a1.y,a2.x,a2.y,a3.x,a3.y,a4.x,a4.y};
        #pragma unroll
        for (int dx = 0; dx < 3; ++dx){
          int k = ic*9 + dy*3 + dx;
          const float* wp = Ws + ot*72 + k;
          float w0 = wp[0], w1 = wp[1152], w2 = wp[2304], w3 = wp[3456];
          #pragma unroll
          for (int p = 0; p < 6; ++p){
            float v = xv[1 + p + dx];
            accC[p][0] += v * w0;
            accC[p][1] += v * w1;
            accC[p][2] += v * w2;
            accC[p][3] += v * w3;
          }
        }
      }
    }
    // two-level accumulation (identical order to R1 -> bitwise-identical output)
    #pragma unroll
    for (int p = 0; p < 6; ++p)
      #pragma unroll
      for (int k = 0; k < 4; ++k){ accM[p][k] += accC[p][k]; accC[p][k] = 0.f; }
  }
  #pragma unroll
  for (int k = 0; k < 4; ++k){
    int oc = oc0 + k*16 + ot;
    float b = Bc[oc];
    float v0 = fmaxf(accM[0][k] + b, 0.f);
    float v1 = fmaxf(accM[1][k] + b, 0.f);
    float v2 = fmaxf(accM[2][k] + b, 0.f);
    float v3 = fmaxf(accM[3][k] + b, 0.f);
    float v4 = fmaxf(accM[4][k] + b, 0.f);
    float v5 = fmaxf(accM[5][k] + b, 0.f);
    float2* yp = reinterpret_cast<float2*>(Y + oc*HW + y0*WW + xs);
    yp[0] = make_float2(v0, v1);
    yp[1] = make_float2(v2, v3);
    yp[2] = make_float2(v4, v5);
  }
}

// ---------------- K2: 1x1 heads + softmax + box decode ----------------
__global__ __launch_bounds__(256) void k_head(
    const float* __restrict__ Y, const float* __restrict__ cw,
    const float* __restrict__ cb, const float* __restrict__ bw,
    const float* __restrict__ bb, const float* __restrict__ info,
    float* __restrict__ scores, float4* __restrict__ boxes)
{
  __shared__ float Ys[4096];
  __shared__ float Wsh[4096];
  const int tid = threadIdx.x;
  const int p0  = blockIdx.x * 64;
  const int po  = tid & 15;
  const int oj  = tid >> 4;
  float accM[4][4], accC[4][4];
  #pragma unroll
  for (int p = 0; p < 4; ++p)
    #pragma unroll
    for (int k = 0; k < 4; ++k){ accM[p][k] = 0.f; accC[p][k] = 0.f; }

  for (int c0 = 0; c0 < CC; c0 += 64){
    __syncthreads();
    for (int i = tid; i < 4096; i += 256){
      int c = i >> 6, p = i & 63;
      Ys[i] = Y[(c0 + c) * HW + p0 + p];
    }
    for (int i = tid; i < 4096; i += 256){
      int c = i >> 6, o = i & 63;
      int gc = c0 + c;
      float v = 0.f;
      if (o < 18) v = cw[o * 512 + gc];
      else if (o < 54) v = bw[(o - 18) * 512 + gc];
      Wsh[i] = v;
    }
    __syncthreads();
    for (int c = 0; c < 64; ++c){
      const float4 xv = *reinterpret_cast<const float4*>(Ys + c*64 + po*4);
      float xa[4] = {xv.x, xv.y, xv.z, xv.w};
      const float* wrd = Wsh + c*64 + oj;
      float wv[4] = {wrd[0], wrd[16], wrd[32], wrd[48]};
      #pragma unroll
      for (int p = 0; p < 4; ++p)
        #pragma unroll
        for (int k = 0; k < 4; ++k)
          accC[p][k] += xa[p] * wv[k];
    }
    #pragma unroll
    for (int p = 0; p < 4; ++p)
      #pragma unroll
      for (int k = 0; k < 4; ++k){ accM[p][k] += accC[p][k]; accC[p][k] = 0.f; }
  }
  __syncthreads();
  #pragma unroll
  for (int p = 0; p < 4; ++p)
    #pragma unroll
    for (int k = 0; k < 4; ++k){
      int o = oj + 16*k;
      float bias = (o < 18) ? cb[o] : ((o < 54) ? bb[o - 18] : 0.f);
      Ys[(po*4 + p)*64 + o] = accM[p][k] + bias;
    }
  __syncthreads();
  float imH = info[0], imW = info[1], imS = info[2];
  for (int it = tid; it < 576; it += 256){
    int pl = it / 9;
    int a  = it - pl*9;
    const float* L = Ys + pl*64;
    float l0 = L[a], l1 = L[9 + a];
    float mx = fmaxf(l0, l1);
    float e0 = expf(l0 - mx), e1 = expf(l1 - mx);
    float sc = e1 / (e0 + e1);
    float d0 = L[18 + a*4 + 0], d1 = L[18 + a*4 + 1];
    float d2 = L[18 + a*4 + 2], d3 = L[18 + a*4 + 3];
    int pos = p0 + pl;
    int yy = pos / 96;
    int xx = pos - yy * 96;
    float aw = c_aw[a], ah = c_ah[a];
    float acx = (float)(xx * 16 + 8);
    float acy = (float)(yy * 16 + 8);
    float cx = __fadd_rn(__fmul_rn(d0, aw), acx);
    float cy = __fadd_rn(__fmul_rn(d1, ah), acy);
    float pw = __fmul_rn(expf(d2), aw);
    float ph = __fmul_rn(expf(d3), ah);
    float hx = __fmul_rn(0.5f, pw);
    float hy = __fmul_rn(0.5f, ph);
    float x1 = fminf(fmaxf(__fadd_rn(cx, -hx), 0.f), imW - 1.f);
    float y1 = fminf(fmaxf(__fadd_rn(cy, -hy), 0.f), imH - 1.f);
    float x2 = fminf(fmaxf(__fadd_rn(cx,  hx), 0.f), imW - 1.f);
    float y2 = fminf(fmaxf(__fadd_rn(cy,  hy), 0.f), imH - 1.f);
    float ms = 16.f * imS;
    bool keep = ((x2 - x1 + 1.f) >= ms) && ((y2 - y1 + 1.f) >= ms);
    int g = pos * 9 + a;
    scores[g] = keep ? sc : -__builtin_inff();
    boxes[g]  = make_float4(x1, y1, x2, y2);
  }
}

// ---------------- top-6000 selection ----------------
__device__ __forceinline__ u32 sortkey(float s){
  u32 u = __float_as_uint(s);
  return u ^ ((u & 0x80000000u) ? 0xFFFFFFFFu : 0x80000000u);
}

__global__ __launch_bounds__(256) void k_hist(const float* __restrict__ scores, u32* __restrict__ hist){
  int i = blockIdx.x * 256 + threadIdx.x;
  if (i >= NANCH) return;
  atomicAdd(&hist[sortkey(scores[i]) >> 16], 1u);
}

__global__ __launch_bounds__(1024) void k_thresh1(const u32* __restrict__ hist, u32* __restrict__ ctr){
  __shared__ u32 cs[1024];
  int t = threadIdx.x;
  int b0 = t * 64;
  u32 s = 0;
  for (int i = 0; i < 64; ++i) s += hist[b0 + i];
  cs[t] = s;
  __syncthreads();
  for (int off = 1; off < 1024; off <<= 1){
    u32 v = cs[t];
    u32 ad = (t + off < 1024) ? cs[t + off] : 0u;
    __syncthreads();
    cs[t] = v + ad;
    __syncthreads();
  }
  u32 here  = cs[t];
  u32 after = (t < 1023) ? cs[t + 1] : 0u;
  if (here >= 6000u && after < 6000u){
    u32 acc = after;
    for (int b = b0 + 63; b >= b0; --b){
      u32 h = hist[b];
      acc += h;
      if (acc >= 6000u){ ctr[1] = (u32)b; ctr[2] = acc - h; break; }
    }
  }
  if (t == 0 && cs[0] < 6000u){ ctr[1] = 0u; ctr[2] = 0u; }
}

__global__ __launch_bounds__(256) void k_hist2(const float* __restrict__ scores,
                                               const u32* __restrict__ ctr, u32* __restrict__ hist2){
  int i = blockIdx.x * 256 + threadIdx.x;
  if (i >= NANCH) return;
  u32 key = sortkey(scores[i]);
  if ((key >> 16) == ctr[1]) atomicAdd(&hist2[key & 0xFFFFu], 1u);
}

__global__ __launch_bounds__(1024) void k_thresh2(const u32* __restrict__ hist2, u32* __restrict__ ctr){
  __shared__ u32 cs[1024];
  int t = threadIdx.x;
  u32 above  = ctr[2];
  u32 target = 6000u - above;
  int b0 = t * 64;
  u32 s = 0;
  for (int i = 0; i < 64; ++i) s += hist2[b0 + i];
  cs[t] = s;
  __syncthreads();
  for (int off = 1; off < 1024; off <<= 1){
    u32 v = cs[t];
    u32 ad = (t + off < 1024) ? cs[t + off] : 0u;
    __syncthreads();
    cs[t] = v + ad;
    __syncthreads();
  }
  u32 here  = cs[t];
  u32 after = (t < 1023) ? cs[t + 1] : 0u;
  if (here >= target && after < target){
    u32 acc = after;
    for (int b = b0 + 63; b >= b0; --b){
      u32 h = hist2[b];
      acc += h;
      if (acc >= target){ ctr[3] = (ctr[1] << 16) | (u32)b; break; }
    }
  }
  if (t == 0 && cs[0] < target) ctr[3] = (ctr[1] << 16);
  if (t == 0) ctr[4] = 6000u;   // init finite-count for k_sort's atomicMin
}

__global__ __launch_bounds__(256) void k_compact(const float* __restrict__ scores,
                                                 u32* __restrict__ ctr, u64* __restrict__ keys){
  int i = blockIdx.x * 256 + threadIdx.x;
  if (i >= NANCH) return;
  u32 key = sortkey(scores[i]);
  if (key >= ctr[3]){
    u32 pos = atomicAdd(&ctr[0], 1u);
    if (pos < CAP) keys[pos] = ((u64)key << 32) | (u64)(u32)(~(u32)i);
  }
}

// single-block bitonic sort of 8192 u64 keys (desc), then gather top-6000 boxes+areas
__global__ __launch_bounds__(1024) void k_sort(const u64* __restrict__ keys, u32* __restrict__ ctr,
                                               const float4* __restrict__ boxes,
                                               float4* __restrict__ topB, float* __restrict__ topA){
  __shared__ u64 sk[CAP];   // 64 KB
  int t = threadIdx.x;
  u32 count = ctr[0]; if (count > CAP) count = CAP;
  for (int i = t; i < CAP; i += 1024)
    sk[i] = (i < (int)count) ? keys[i] : 0ull;
  __syncthreads();
  for (int k = 2; k <= CAP; k <<= 1){
    for (int j = k >> 1; j > 0; j >>= 1){
      for (int i = t; i < CAP; i += 1024){
        int l = i ^ j;
        if (l > i){
          u64 a = sk[i], b2 = sk[l];
          bool sw = ((i & k) == 0) ? (a < b2) : (a > b2);
          if (sw){ sk[i] = b2; sk[l] = a; }
        }
      }
      __syncthreads();
    }
  }
  for (int r = t; r < PRE; r += 1024){
    u64 key = sk[r];
    float4 bv = make_float4(0.f, 0.f, 0.f, 0.f);
    float area = 1.f;
    if (!((key >> 32) & 0x80000000ull))
      atomicMin((int*)(ctr + 4), r);     // first non-finite (or padding) rank
    if (r < (int)count && (key >> 32) != 0ull){
      u32 idx = ~(u32)key;
      if (idx < NANCH){
        bv = boxes[idx];
        area = (bv.z - bv.x + 1.f) * (bv.w - bv.y + 1.f);
      }
    }
    topB[r] = bv;
    topA[r] = area;
  }
}

// ---------------- NMS stage A: suppression bit-matrix M[6000][188] ----------------
// lanes 0..31 = 32 consecutive rows sharing one j-word -> LDS reads broadcast.
__global__ __launch_bounds__(256) void k_iou(const float4* __restrict__ topB, const float* __restrict__ topA,
                                             u32* __restrict__ M){
  __shared__ float jx1[2048], jy1[2048], jx2[2048], jy2[2048], ja[2048]; // 40 KB
  const int tid = threadIdx.x;
  const int rr  = tid & 31;
  const int wg  = tid >> 5;
  const int i   = blockIdx.x * 32 + rr;
  float4 bi = make_float4(0.f,0.f,0.f,0.f); float ai = 1.f;
  if (i < PRE){ bi = topB[i]; ai = topA[i]; }
  for (int t0 = 0; t0 < 3; ++t0){
    __syncthreads();
    for (int s = tid; s < 2048; s += 256){
      int j = t0*2048 + s;
      float4 b = make_float4(0.f,0.f,0.f,0.f); float a = 1.f;
      if (j < PRE){ b = topB[j]; a = topA[j]; }
      jx1[s]=b.x; jy1[s]=b.y; jx2[s]=b.z; jy2[s]=b.w; ja[s]=a;
    }
    __syncthreads();
    if (i >= PRE) continue;
    #pragma unroll
    for (int m = 0; m < 8; ++m){
      int w = t0*64 + wg + 8*m;
      if (w >= 188) continue;
      int jbase = w * 32;
      if (jbase + 31 <= i){ M[(size_t)i*188 + w] = 0u; continue; }
      u32 bits = 0u;
      for (int s = 0; s < 32; ++s){
        int j = jbase + s;
        if (j <= i || j >= PRE) continue;
        int jl = j - t0*2048;
        float xx1 = fmaxf(bi.x, jx1[jl]);
        float yy1 = fmaxf(bi.y, jy1[jl]);
        float xx2 = fminf(bi.z, jx2[jl]);
        float yy2 = fminf(bi.w, jy2[jl]);
        float iw = fmaxf(xx2 - xx1 + 1.f, 0.f);
        float ih = fmaxf(yy2 - yy1 + 1.f, 0.f);
        float inter = iw * ih;
        float iou = inter / (ai + ja[jl] - inter);
        if (iou > 0.7f) bits |= (1u << s);
      }
      M[(size_t)i*188 + w] = bits;
    }
  }
}

// ---------------- NMS stage B: single-wave greedy reduce (wave-synchronous) ----------------
__global__ __launch_bounds__(64) void k_reduce(const u32* __restrict__ M, const float4* __restrict__ topB,
                                               const u32* __restrict__ ctr, float* __restrict__ out){
  __shared__ u32 supp[192];
  __shared__ int kept[POST];
  const int t = threadIdx.x;
  int validN = (int)ctr[0];
  int finN   = (int)ctr[4];
  if (finN < validN) validN = finN;
  if (validN > PRE)  validN = PRE;
  for (int w = t; w < 192; w += 64){
    int lo = w * 32;
    u32 v;
    if (lo + 32 <= validN) v = 0u;
    else if (lo >= validN) v = 0xFFFFFFFFu;
    else v = ~((1u << (validN - lo)) - 1u);
    supp[w] = v;
  }
  __syncthreads();
  int p = 0;
  for (int k = 0; k < POST; ++k){
    int i = -1;
    int wp = p >> 5;                  // bits < p are always already set
    while (wp < 188){
      int w = wp + t;
      u32 v = (w < 188) ? supp[w] : 0xFFFFFFFFu;
      u64 bal = __ballot(v != 0xFFFFFFFFu);
      if (bal){
        int lf = (int)__ffsll((unsigned long long)bal) - 1;
        u32 vs = (u32)__shfl((int)v, lf, 64);
        i = (wp + lf) * 32 + (__ffs((int)(~vs)) - 1);
        break;
      }
      wp += 64;
    }
    if (t == 0) kept[k] = i;
    if (i >= 0){
      const u32* row = M + (size_t)i * 188;
      #pragma unroll
      for (int m = 0; m < 3; ++m){
        int w = t + 64*m;
        if (w < 188){
          u32 sv = supp[w] | row[w];
          if (w == (i >> 5)) sv |= 1u << (i & 31);
          supp[w] = sv;
        }
      }
      p = i + 1;
    }
    __syncthreads();
  }
  for (int q = t; q < 1500; q += 64){
    int r = q / 5, c = q - r*5;
    int i = kept[r];
    float v = 0.f;
    if (i >= 0 && c > 0){
      float4 b = topB[i];
      v = (c == 1) ? b.x : (c == 2) ? b.y : (c == 3) ? b.z : b.w;
    }
    out[q] = v;
  }
}

// ---------------- launch ----------------
extern "C" void kernel_launch(void* const* d_in, const int* in_sizes, int n_in,
                              void* d_out, int out_size, void* d_ws, size_t ws_size,
                              hipStream_t stream)
{
  const float* fm   = (const float*)d_in[0];
  const float* info = (const float*)d_in[1];
  const float* cw3  = (const float*)d_in[2];
  const float* cb3  = (const float*)d_in[3];
  const float* clw  = (const float*)d_in[4];
  const float* clb  = (const float*)d_in[5];
  const float* bbw  = (const float*)d_in[6];
  const float* bbb  = (const float*)d_in[7];
  float* out = (float*)d_out;

  char* base = (char*)d_ws;
  u32*   hist   = (u32*)  (base + 0);          // 65536 u32
  u32*   hist2  = (u32*)  (base + 262144);     // 65536 u32
  u32*   ctr    = (u32*)  (base + 524288);     // [0]=count [1]=T16 [2]=above [3]=K32 [4]=finiteN
  float* Y      = (float*)(base + 524544);     // 512*6144 f32 = 12.58 MB
  u32*   M      = (u32*)  (base + 524544);     // overlays Y (dead after k_head): 6000*188*4 = 4.5 MB
  float* scores = (float*)(base + 13107456);   // 55296 f32
  float4* boxes = (float4*)(base + 13328640);  // 55296 f32x4
  u64*   keys   = (u64*)  (base + 14213376);   // 8192 u64
  float4* topB  = (float4*)(base + 14278912);  // 6016 f32x4
  float* topA   = (float*)(base + 14375168);   // 6016 f32
  // total ws use: 14399232 B (~14.4 MB, same as R1)

  hipMemsetAsync(base, 0, 524544, stream);     // hist, hist2, ctr
  k_conv3  <<<dim3(64, 8), 256, 0, stream>>>(fm, cw3, cb3, Y);
  k_head   <<<96,  256, 0, stream>>>(Y, clw, clb, bbw, bbb, info, scores, boxes);
  k_hist   <<<216, 256, 0, stream>>>(scores, hist);
  k_thresh1<<<1,  1024, 0, stream>>>(hist, ctr);
  k_hist2  <<<216, 256, 0, stream>>>(scores, ctr, hist2);
  k_thresh2<<<1,  1024, 0, stream>>>(hist2, ctr);
  k_compact<<<216, 256, 0, stream>>>(scores, ctr, keys);
  k_sort   <<<1,  1024, 0, stream>>>(keys, ctr, boxes, topB, topA);
  k_iou    <<<188, 256, 0, stream>>>(topB, topA, M);
  k_reduce <<<1,    64, 0, stream>>>(M, topB, ctr, out);
}

// Round 3
// 1083.603 us; speedup vs baseline: 1.3848x; 1.2046x over previous
//
#include <hip/hip_runtime.h>
#include <stdint.h>

typedef unsigned int u32;
typedef unsigned long long u64;

#define HH 64
#define WW 96
#define HW 6144
#define CC 512
#define NANCH 55296
#define PRE 6000
#define POST 300
#define CAP 8192

// 9 base anchors (STRIDE=16, scales 8/16/32, ratios .5/1/2), center always (x*16+8, y*16+8).
__device__ __constant__ float c_aw[9] = {184.f,368.f,736.f,128.f,256.f,512.f,88.f,176.f,352.f};
__device__ __constant__ float c_ah[9] = {96.f,192.f,384.f,128.f,256.f,512.f,176.f,352.f,704.f};

// ---------------- K1: 3x3 conv 512->512 + bias + relu ----------------
// R3 tiling: block = 2 output rows x 96 cols x 32 oc, 128 threads (16 colg x 8 ot).
// Thread: 12 positions (6 cols x 2 rows) x 4 oc -> weight LDS reads amortized over
// 12 positions (was 6). Weights in LDS as [oc][icpair-free group=ic][12] padded so
// every 9-tap group reads as b128+b128+b32. X at odd offset o=5 so windows read as
// aligned b64. Per-position FMA order (chunk; ic asc; dy; dx; accC->accM fold per
// chunk) IDENTICAL to R1/R2 -> bit-identical Y.
__global__ __launch_bounds__(128, 1) void k_conv3(
    const float* __restrict__ X, const float* __restrict__ Wt,
    const float* __restrict__ Bc, float* __restrict__ Y)
{
  __shared__ float Xs[8*4*104];   // ic(8) x row(4) x 104 cells; cell = x+5, x in [-1,96]
  __shared__ float Wl[32*96];     // ocl(32) x g(8) x 12 (taps 0..8 used)
  const int tid  = threadIdx.x;
  const int y0   = blockIdx.x * 2;
  const int oc0  = blockIdx.y * 32;
  const int colg = tid & 15;
  const int ot   = tid >> 4;
  const int xs   = colg * 6;

  // zero all of Xs once (pads + OOR rows persist as zeros; valid data overwritten each chunk)
  for (int i = tid; i < 832; i += 128)
    *reinterpret_cast<float4*>(Xs + i*4) = make_float4(0.f,0.f,0.f,0.f);

  float accM[2][6][4], accC[2][6][4];
  #pragma unroll
  for (int r = 0; r < 2; ++r)
    #pragma unroll
    for (int c = 0; c < 6; ++c)
      #pragma unroll
      for (int k = 0; k < 4; ++k){ accM[r][c][k] = 0.f; accC[r][c][k] = 0.f; }

  float4 xr[6]; float4 wr[5];

  auto loadX = [&](int c0){
    #pragma unroll
    for (int n = 0; n < 6; ++n){
      int item = tid + 128*n;          // 768 f4 items: ic(8) x row(4) x 24 f4
      int ic = item / 96, rem = item - ic*96;
      int r = rem / 24, c4 = rem - r*24;
      int row = y0 - 1 + r;
      float4 v = make_float4(0.f,0.f,0.f,0.f);
      if ((unsigned)row < 64u)
        v = *reinterpret_cast<const float4*>(X + (c0+ic)*HW + row*WW + c4*4);
      xr[n] = v;
    }
  };
  auto loadW = [&](int ch){
    #pragma unroll
    for (int n = 0; n < 5; ++n){
      int item = tid + 128*n;          // 576 f4 items: ocl(32) x 18 f4
      if (item < 576){
        int ocl = item / 18, j4 = item - ocl*18;
        wr[n] = *reinterpret_cast<const float4*>(Wt + (oc0+ocl)*4608 + ch*72 + j4*4);
      }
    }
  };
  auto storeXW = [&](int c0){
    #pragma unroll
    for (int n = 0; n < 6; ++n){
      int item = tid + 128*n;
      int ic = item / 96, rem = item - ic*96;
      int r = rem / 24, c4 = rem - r*24;
      int row = y0 - 1 + r;
      if ((unsigned)row < 64u){
        float* dst = Xs + ic*416 + r*104 + 5 + c4*4;
        dst[0] = xr[n].x; dst[1] = xr[n].y; dst[2] = xr[n].z; dst[3] = xr[n].w;
      }
    }
    #pragma unroll
    for (int n = 0; n < 5; ++n){
      int item = tid + 128*n;
      if (item < 576){
        int ocl = item / 18, j4 = item - ocl*18;
        float v[4] = {wr[n].x, wr[n].y, wr[n].z, wr[n].w};
        #pragma unroll
        for (int l = 0; l < 4; ++l){
          int j = j4*4 + l;            // 0..71
          int g = j / 9, u = j - g*9;
          Wl[ocl*96 + g*12 + u] = v[l];
        }
      }
    }
  };

  loadX(0); loadW(0);
  for (int ch = 0; ch < 64; ++ch){
    __syncthreads();
    storeXW(ch);
    __syncthreads();
    if (ch < 63){ loadX((ch+1)*8); loadW(ch+1); }
    #pragma unroll
    for (int p = 0; p < 4; ++p){
      #pragma unroll
      for (int i = 0; i < 2; ++i){
        const int g = 2*p + i;         // local ic 0..7, ascending
        float xv[4][8];
        #pragma unroll
        for (int r = 0; r < 4; ++r){
          const float2* xp = reinterpret_cast<const float2*>(Xs + g*416 + r*104 + xs + 4);
          float2 a0 = xp[0], a1 = xp[1], a2 = xp[2], a3 = xp[3];
          xv[r][0]=a0.x; xv[r][1]=a0.y; xv[r][2]=a1.x; xv[r][3]=a1.y;
          xv[r][4]=a2.x; xv[r][5]=a2.y; xv[r][6]=a3.x; xv[r][7]=a3.y;
        }
        #pragma unroll
        for (int ko = 0; ko < 4; ++ko){
          const float* wb = Wl + (ot + 8*ko)*96 + g*12;
          float4 w03 = *reinterpret_cast<const float4*>(wb);
          float4 w47 = *reinterpret_cast<const float4*>(wb + 4);
          float w8 = wb[8];
          float wv[9] = {w03.x,w03.y,w03.z,w03.w,w47.x,w47.y,w47.z,w47.w,w8};
          #pragma unroll
          for (int dy = 0; dy < 3; ++dy){
            #pragma unroll
            for (int dx = 0; dx < 3; ++dx){
              float w = wv[dy*3+dx];
              #pragma unroll
              for (int r = 0; r < 2; ++r)
                #pragma unroll
                for (int c = 0; c < 6; ++c)
                  accC[r][c][ko] += xv[r+dy][c+dx] * w;
            }
          }
        }
      }
    }
    // two-level fold, once per 8-ic chunk (identical order to R1/R2)
    #pragma unroll
    for (int r = 0; r < 2; ++r)
      #pragma unroll
      for (int c = 0; c < 6; ++c)
        #pragma unroll
        for (int k = 0; k < 4; ++k){ accM[r][c][k] += accC[r][c][k]; accC[r][c][k] = 0.f; }
  }
  #pragma unroll
  for (int ko = 0; ko < 4; ++ko){
    int oc = oc0 + ot + 8*ko;
    float b = Bc[oc];
    #pragma unroll
    for (int r = 0; r < 2; ++r){
      float v0 = fmaxf(accM[r][0][ko] + b, 0.f);
      float v1 = fmaxf(accM[r][1][ko] + b, 0.f);
      float v2 = fmaxf(accM[r][2][ko] + b, 0.f);
      float v3 = fmaxf(accM[r][3][ko] + b, 0.f);
      float v4 = fmaxf(accM[r][4][ko] + b, 0.f);
      float v5 = fmaxf(accM[r][5][ko] + b, 0.f);
      float2* yp = reinterpret_cast<float2*>(Y + oc*HW + (y0+r)*WW + xs);
      yp[0] = make_float2(v0, v1);
      yp[1] = make_float2(v2, v3);
      yp[2] = make_float2(v4, v5);
    }
  }
}

// ---------------- K2: 1x1 heads + softmax + box decode (+ hist, merged) ----------------
__device__ __forceinline__ u32 sortkey(float s){
  u32 u = __float_as_uint(s);
  return u ^ ((u & 0x80000000u) ? 0xFFFFFFFFu : 0x80000000u);
}

__global__ __launch_bounds__(256) void k_head(
    const float* __restrict__ Y, const float* __restrict__ cw,
    const float* __restrict__ cb, const float* __restrict__ bw,
    const float* __restrict__ bb, const float* __restrict__ info,
    float* __restrict__ scores, float4* __restrict__ boxes, u32* __restrict__ hist)
{
  __shared__ float Ys[4096];
  __shared__ float Wsh[4096];
  const int tid = threadIdx.x;
  const int p0  = blockIdx.x * 64;
  const int po  = tid & 15;
  const int oj  = tid >> 4;
  float accM[4][4], accC[4][4];
  #pragma unroll
  for (int p = 0; p < 4; ++p)
    #pragma unroll
    for (int k = 0; k < 4; ++k){ accM[p][k] = 0.f; accC[p][k] = 0.f; }

  for (int c0 = 0; c0 < CC; c0 += 64){
    __syncthreads();
    for (int i = tid; i < 4096; i += 256){
      int c = i >> 6, p = i & 63;
      Ys[i] = Y[(c0 + c) * HW + p0 + p];
    }
    for (int i = tid; i < 4096; i += 256){
      int c = i >> 6, o = i & 63;
      int gc = c0 + c;
      float v = 0.f;
      if (o < 18) v = cw[o * 512 + gc];
      else if (o < 54) v = bw[(o - 18) * 512 + gc];
      Wsh[i] = v;
    }
    __syncthreads();
    for (int c = 0; c < 64; ++c){
      const float4 xv = *reinterpret_cast<const float4*>(Ys + c*64 + po*4);
      float xa[4] = {xv.x, xv.y, xv.z, xv.w};
      const float* wrd = Wsh + c*64 + oj;
      float wv[4] = {wrd[0], wrd[16], wrd[32], wrd[48]};
      #pragma unroll
      for (int p = 0; p < 4; ++p)
        #pragma unroll
        for (int k = 0; k < 4; ++k)
          accC[p][k] += xa[p] * wv[k];
    }
    #pragma unroll
    for (int p = 0; p < 4; ++p)
      #pragma unroll
      for (int k = 0; k < 4; ++k){ accM[p][k] += accC[p][k]; accC[p][k] = 0.f; }
  }
  __syncthreads();
  #pragma unroll
  for (int p = 0; p < 4; ++p)
    #pragma unroll
    for (int k = 0; k < 4; ++k){
      int o = oj + 16*k;
      float bias = (o < 18) ? cb[o] : ((o < 54) ? bb[o - 18] : 0.f);
      Ys[(po*4 + p)*64 + o] = accM[p][k] + bias;
    }
  __syncthreads();
  float imH = info[0], imW = info[1], imS = info[2];
  for (int it = tid; it < 576; it += 256){
    int pl = it / 9;
    int a  = it - pl*9;
    const float* L = Ys + pl*64;
    float l0 = L[a], l1 = L[9 + a];
    float mx = fmaxf(l0, l1);
    float e0 = expf(l0 - mx), e1 = expf(l1 - mx);
    float sc = e1 / (e0 + e1);
    float d0 = L[18 + a*4 + 0], d1 = L[18 + a*4 + 1];
    float d2 = L[18 + a*4 + 2], d3 = L[18 + a*4 + 3];
    int pos = p0 + pl;
    int yy = pos / 96;
    int xx = pos - yy * 96;
    float aw = c_aw[a], ah = c_ah[a];
    float acx = (float)(xx * 16 + 8);
    float acy = (float)(yy * 16 + 8);
    float cx = __fadd_rn(__fmul_rn(d0, aw), acx);
    float cy = __fadd_rn(__fmul_rn(d1, ah), acy);
    float pw = __fmul_rn(expf(d2), aw);
    float ph = __fmul_rn(expf(d3), ah);
    float hx = __fmul_rn(0.5f, pw);
    float hy = __fmul_rn(0.5f, ph);
    float x1 = fminf(fmaxf(__fadd_rn(cx, -hx), 0.f), imW - 1.f);
    float y1 = fminf(fmaxf(__fadd_rn(cy, -hy), 0.f), imH - 1.f);
    float x2 = fminf(fmaxf(__fadd_rn(cx,  hx), 0.f), imW - 1.f);
    float y2 = fminf(fmaxf(__fadd_rn(cy,  hy), 0.f), imH - 1.f);
    float ms = 16.f * imS;
    bool keep = ((x2 - x1 + 1.f) >= ms) && ((y2 - y1 + 1.f) >= ms);
    int g = pos * 9 + a;
    float val = keep ? sc : -__builtin_inff();
    scores[g] = val;
    boxes[g]  = make_float4(x1, y1, x2, y2);
    atomicAdd(&hist[sortkey(val) >> 16], 1u);
  }
}

// ---------------- top-6000 selection ----------------
__global__ __launch_bounds__(1024) void k_thresh1(const u32* __restrict__ hist, u32* __restrict__ ctr){
  __shared__ u32 cs[1024];
  int t = threadIdx.x;
  int b0 = t * 64;
  u32 s = 0;
  for (int i = 0; i < 64; ++i) s += hist[b0 + i];
  cs[t] = s;
  __syncthreads();
  for (int off = 1; off < 1024; off <<= 1){
    u32 v = cs[t];
    u32 ad = (t + off < 1024) ? cs[t + off] : 0u;
    __syncthreads();
    cs[t] = v + ad;
    __syncthreads();
  }
  u32 here  = cs[t];
  u32 after = (t < 1023) ? cs[t + 1] : 0u;
  if (here >= 6000u && after < 6000u){
    u32 acc = after;
    for (int b = b0 + 63; b >= b0; --b){
      u32 h = hist[b];
      acc += h;
      if (acc >= 6000u){ ctr[1] = (u32)b; ctr[2] = acc - h; break; }
    }
  }
  if (t == 0 && cs[0] < 6000u){ ctr[1] = 0u; ctr[2] = 0u; }
}

__global__ __launch_bounds__(256) void k_hist2(const float* __restrict__ scores,
                                               const u32* __restrict__ ctr, u32* __restrict__ hist2){
  int i = blockIdx.x * 256 + threadIdx.x;
  if (i >= NANCH) return;
  u32 key = sortkey(scores[i]);
  if ((key >> 16) == ctr[1]) atomicAdd(&hist2[key & 0xFFFFu], 1u);
}

__global__ __launch_bounds__(1024) void k_thresh2(const u32* __restrict__ hist2, u32* __restrict__ ctr){
  __shared__ u32 cs[1024];
  int t = threadIdx.x;
  u32 above  = ctr[2];
  u32 target = 6000u - above;
  int b0 = t * 64;
  u32 s = 0;
  for (int i = 0; i < 64; ++i) s += hist2[b0 + i];
  cs[t] = s;
  __syncthreads();
  for (int off = 1; off < 1024; off <<= 1){
    u32 v = cs[t];
    u32 ad = (t + off < 1024) ? cs[t + off] : 0u;
    __syncthreads();
    cs[t] = v + ad;
    __syncthreads();
  }
  u32 here  = cs[t];
  u32 after = (t < 1023) ? cs[t + 1] : 0u;
  if (here >= target && after < target){
    u32 acc = after;
    for (int b = b0 + 63; b >= b0; --b){
      u32 h = hist2[b];
      acc += h;
      if (acc >= target){ ctr[3] = (ctr[1] << 16) | (u32)b; break; }
    }
  }
  if (t == 0 && cs[0] < target) ctr[3] = (ctr[1] << 16);
  if (t == 0) ctr[4] = 6000u;
}

__global__ __launch_bounds__(256) void k_compact(const float* __restrict__ scores,
                                                 u32* __restrict__ ctr, u64* __restrict__ keys){
  int i = blockIdx.x * 256 + threadIdx.x;
  if (i >= NANCH) return;
  u32 key = sortkey(scores[i]);
  if (key >= ctr[3]){
    u32 pos = atomicAdd(&ctr[0], 1u);
    if (pos < CAP) keys[pos] = ((u64)key << 32) | (u64)(u32)(~(u32)i);
  }
}

// single-block bitonic sort, 8192 u64 desc; reg-resident phases for j<=4 (and k<=8)
__global__ __launch_bounds__(1024) void k_sort(const u64* __restrict__ keys, u32* __restrict__ ctr,
                                               const float4* __restrict__ boxes,
                                               float4* __restrict__ topB, float* __restrict__ topA){
  __shared__ u64 sk[CAP];   // 64 KB
  int t = threadIdx.x;
  u32 count = ctr[0]; if (count > CAP) count = CAP;
  for (int i = t; i < CAP; i += 1024)
    sk[i] = (i < (int)count) ? keys[i] : 0ull;
  __syncthreads();

  const int b = t * 8;
  u64 e[8];
  // phases k=2,4,8 entirely in registers
  #pragma unroll
  for (int m = 0; m < 8; ++m) e[m] = sk[b + m];
  #pragma unroll
  for (int kk = 1; kk <= 3; ++kk){
    int k = 1 << kk;
    for (int j = k >> 1; j > 0; j >>= 1){
      #pragma unroll
      for (int x = 0; x < 8; ++x){
        int y = x ^ j;
        if (y > x){
          bool up = (((b + x) & k) == 0);
          u64 a = e[x], c = e[y];
          bool sw = up ? (a < c) : (a > c);
          if (sw){ e[x] = c; e[y] = a; }
        }
      }
    }
  }
  #pragma unroll
  for (int m = 0; m < 8; ++m) sk[b + m] = e[m];
  __syncthreads();

  for (int k = 16; k <= CAP; k <<= 1){
    for (int j = k >> 1; j >= 8; j >>= 1){
      for (int q = t; q < CAP/2; q += 1024){
        int i = ((q & ~(j - 1)) << 1) | (q & (j - 1));
        int l = i + j;
        u64 a = sk[i], c = sk[l];
        bool sw = ((i & k) == 0) ? (a < c) : (a > c);
        if (sw){ sk[i] = c; sk[l] = a; }
      }
      __syncthreads();
    }
    // j = 4,2,1 in registers; direction uniform per 8-block for k>=16
    #pragma unroll
    for (int m = 0; m < 8; ++m) e[m] = sk[b + m];
    {
      bool up = ((b & k) == 0);
      #pragma unroll
      for (int j = 4; j > 0; j >>= 1){
        #pragma unroll
        for (int x = 0; x < 8; ++x){
          int y = x ^ j;
          if (y > x){
            u64 a = e[x], c = e[y];
            bool sw = up ? (a < c) : (a > c);
            if (sw){ e[x] = c; e[y] = a; }
          }
        }
      }
    }
    #pragma unroll
    for (int m = 0; m < 8; ++m) sk[b + m] = e[m];
    __syncthreads();
  }

  for (int r = t; r < PRE; r += 1024){
    u64 key = sk[r];
    float4 bv = make_float4(0.f, 0.f, 0.f, 0.f);
    float area = 1.f;
    if (!((key >> 32) & 0x80000000ull))
      atomicMin((int*)(ctr + 4), r);     // first non-finite (or padding) rank
    if (r < (int)count && (key >> 32) != 0ull){
      u32 idx = ~(u32)key;
      if (idx < NANCH){
        bv = boxes[idx];
        area = (bv.z - bv.x + 1.f) * (bv.w - bv.y + 1.f);
      }
    }
    topB[r] = bv;
    topA[r] = area;
  }
}

// ---------------- NMS stage A: suppression bit-matrix M[6000][188] ----------------
__global__ __launch_bounds__(256) void k_iou(const float4* __restrict__ topB, const float* __restrict__ topA,
                                             u32* __restrict__ M){
  __shared__ float4 jb[3072];   // 48 KB
  const int tid = threadIdx.x;
  const int rr  = tid & 31;
  const int wg  = tid >> 5;
  const int i   = blockIdx.x * 32 + rr;
  float4 bi = make_float4(0.f,0.f,0.f,0.f); float ai = 1.f;
  if (i < PRE){ bi = topB[i]; ai = topA[i]; }
  for (int ph = 0; ph < 2; ++ph){
    __syncthreads();
    for (int s = tid; s < 3072; s += 256){
      int j = ph*3072 + s;
      jb[s] = (j < PRE) ? topB[j] : make_float4(0.f,0.f,0.f,0.f);
    }
    __syncthreads();
    if (i >= PRE) continue;
    int nw = (ph == 0) ? 96 : 92;
    #pragma unroll
    for (int m = 0; m < 12; ++m){
      int wl = wg + 8*m;
      if (wl >= nw) continue;
      int w = ph*96 + wl;
      int jbase = w * 32;
      if (jbase + 31 <= i){ M[(size_t)i*188 + w] = 0u; continue; }
      u32 bits = 0u;
      for (int s = 0; s < 32; ++s){
        int j = jbase + s;
        if (j <= i || j >= PRE) continue;
        float4 bj = jb[j - ph*3072];
        float aj = (bj.z - bj.x + 1.f) * (bj.w - bj.y + 1.f);  // bit-identical to topA expr
        float xx1 = fmaxf(bi.x, bj.x);
        float yy1 = fmaxf(bi.y, bj.y);
        float xx2 = fminf(bi.z, bj.z);
        float yy2 = fminf(bi.w, bj.w);
        float iw = fmaxf(xx2 - xx1 + 1.f, 0.f);
        float ih = fmaxf(yy2 - yy1 + 1.f, 0.f);
        float inter = iw * ih;
        float iou = inter / (ai + aj - inter);
        if (iou > 0.7f) bits |= (1u << s);
      }
      M[(size_t)i*188 + w] = bits;
    }
  }
}

// ---------------- NMS stage B: single-wave register-resident greedy scan ----------------
__global__ __launch_bounds__(64) void k_reduce(const u32* __restrict__ M, const float4* __restrict__ topB,
                                               const u32* __restrict__ ctr, float* __restrict__ out){
  __shared__ int kept[POST];
  const int t = threadIdx.x;
  int validN = (int)ctr[0];
  int finN   = (int)ctr[4];
  if (finN < validN) validN = finN;
  if (validN > PRE)  validN = PRE;
  auto initw = [&](int w)->u32{
    if (w >= 188) return 0xFFFFFFFFu;
    int lo = w * 32;
    if (lo + 32 <= validN) return 0u;
    if (lo >= validN) return 0xFFFFFFFFu;
    return ~((1u << (validN - lo)) - 1u);
  };
  u32 s0 = initw(t), s1 = initw(64 + t), s2 = initw(128 + t);
  for (int k = 0; k < POST; ++k){
    int i = -1;
    u64 b0 = __ballot(s0 != 0xFFFFFFFFu);
    if (b0){
      int L = (int)__ffsll((unsigned long long)b0) - 1;
      u32 v = (u32)__shfl((int)s0, L, 64);
      i = L*32 + (__ffs((int)(~v)) - 1);
    } else {
      u64 b1 = __ballot(s1 != 0xFFFFFFFFu);
      if (b1){
        int L = (int)__ffsll((unsigned long long)b1) - 1;
        u32 v = (u32)__shfl((int)s1, L, 64);
        i = 2048 + L*32 + (__ffs((int)(~v)) - 1);
      } else {
        u64 b2 = __ballot(s2 != 0xFFFFFFFFu);
        if (b2){
          int L = (int)__ffsll((unsigned long long)b2) - 1;
          u32 v = (u32)__shfl((int)s2, L, 64);
          i = 4096 + L*32 + (__ffs((int)(~v)) - 1);
        }
      }
    }
    if (t == 0) kept[k] = i;
    if (i >= 0){
      const u32* row = M + (size_t)i * 188;
      u32 r0 = row[t];
      u32 r1 = (64 + t < 188) ? row[64 + t] : 0u;
      u32 r2 = (128 + t < 188) ? row[128 + t] : 0u;
      s0 |= r0; s1 |= r1; s2 |= r2;
      int iw = i >> 5, ib = i & 31;
      if (iw == t) s0 |= (1u << ib);
      else if (iw == 64 + t) s1 |= (1u << ib);
      else if (iw == 128 + t) s2 |= (1u << ib);
    }
  }
  __syncthreads();
  for (int q = t; q < 1500; q += 64){
    int r = q / 5, c = q - r*5;
    int i = kept[r];
    float v = 0.f;
    if (i >= 0 && c > 0){
      float4 bx = topB[i];
      v = (c == 1) ? bx.x : (c == 2) ? bx.y : (c == 3) ? bx.z : bx.w;
    }
    out[q] = v;
  }
}

// ---------------- launch ----------------
extern "C" void kernel_launch(void* const* d_in, const int* in_sizes, int n_in,
                              void* d_out, int out_size, void* d_ws, size_t ws_size,
                              hipStream_t stream)
{
  const float* fm   = (const float*)d_in[0];
  const float* info = (const float*)d_in[1];
  const float* cw3  = (const float*)d_in[2];
  const float* cb3  = (const float*)d_in[3];
  const float* clw  = (const float*)d_in[4];
  const float* clb  = (const float*)d_in[5];
  const float* bbw  = (const float*)d_in[6];
  const float* bbb  = (const float*)d_in[7];
  float* out = (float*)d_out;

  char* base = (char*)d_ws;
  u32*   hist   = (u32*)  (base + 0);          // 65536 u32
  u32*   hist2  = (u32*)  (base + 262144);     // 65536 u32
  u32*   ctr    = (u32*)  (base + 524288);     // [0]=count [1]=T16 [2]=above [3]=K32 [4]=finiteN
  float* Y      = (float*)(base + 524544);     // 512*6144 f32 = 12.58 MB
  u32*   M      = (u32*)  (base + 524544);     // overlays Y (dead after k_head): 4.5 MB
  float* scores = (float*)(base + 13107456);   // 55296 f32
  float4* boxes = (float4*)(base + 13328640);  // 55296 f32x4
  u64*   keys   = (u64*)  (base + 14213376);   // 8192 u64
  float4* topB  = (float4*)(base + 14278912);  // 6016 f32x4
  float* topA   = (float*)(base + 14375168);   // 6016 f32
  // total ws use: 14399232 B (~14.4 MB, same as R1/R2)

  hipMemsetAsync(base, 0, 524544, stream);     // hist, hist2, ctr
  k_conv3  <<<dim3(32, 16), 128, 0, stream>>>(fm, cw3, cb3, Y);
  k_head   <<<96,  256, 0, stream>>>(Y, clw, clb, bbw, bbb, info, scores, boxes, hist);
  k_thresh1<<<1,  1024, 0, stream>>>(hist, ctr);
  k_hist2  <<<216, 256, 0, stream>>>(scores, ctr, hist2);
  k_thresh2<<<1,  1024, 0, stream>>>(hist2, ctr);
  k_compact<<<216, 256, 0, stream>>>(scores, ctr, keys);
  k_sort   <<<1,  1024, 0, stream>>>(keys, ctr, boxes, topB, topA);
  k_iou    <<<188, 256, 0, stream>>>(topB, topA, M);
  k_reduce <<<1,    64, 0, stream>>>(M, topB, ctr, out);
}

// Round 4
// 980.095 us; speedup vs baseline: 1.5311x; 1.1056x over previous
//
#include <hip/hip_runtime.h>
#include <stdint.h>

typedef unsigned int u32;
typedef unsigned long long u64;

#define HH 64
#define WW 96
#define HW 6144
#define CC 512
#define NANCH 55296
#define PRE 6000
#define POST 300
#define CAP 8192

// 9 base anchors (STRIDE=16, scales 8/16/32, ratios .5/1/2), center always (x*16+8, y*16+8).
__device__ __constant__ float c_aw[9] = {184.f,368.f,736.f,128.f,256.f,512.f,88.f,176.f,352.f};
__device__ __constant__ float c_ah[9] = {96.f,192.f,384.f,128.f,256.f,512.f,176.f,352.f,704.f};

// ---------------- K1: 3x3 conv 512->512 + bias + relu ----------------
// R4: block = 256 thr (16 colg x 16 ot), tile 2 rows x 96 cols x 32 oc,
// thread = 6 cols x 2 rows x 2 oc (oc = oc0 + ot + 16*ko). Grid 32x16 = 512
// blocks x 4 waves = 2048 waves = 8/CU = 2/SIMD (R3 had 1/SIMD -> no hiding).
// Wl stride 100 words (== 4 mod 32): weight b128 reads 2-way max (R3's stride
// 96 == 0 mod 32 was 8-way conflicted). Per-element FMA order (chunk; ic asc;
// dy; dx; chunk-fold) IDENTICAL to R1-R3 -> bit-identical Y.
__global__ __launch_bounds__(256, 2) void k_conv3(
    const float* __restrict__ X, const float* __restrict__ Wt,
    const float* __restrict__ Bc, float* __restrict__ Y)
{
  __shared__ float Xs[8*4*104];   // ic(8) x row(4) x 104 cells; cell = x+5, x in [-1,96]; 13.3 KB
  __shared__ float Wl[32*100];    // ocl(32) x (g(8) x 12 + pad); 12.8 KB
  const int tid  = threadIdx.x;
  const int y0   = blockIdx.x * 2;
  const int oc0  = blockIdx.y * 32;
  const int colg = tid & 15;
  const int ot   = tid >> 4;      // 0..15
  const int xs   = colg * 6;

  // zero Xs once: pads + out-of-range rows persist as zeros
  for (int i = tid; i < 832; i += 256)
    *reinterpret_cast<float4*>(Xs + i*4) = make_float4(0.f,0.f,0.f,0.f);

  float accM[2][6][2], accC[2][6][2];
  #pragma unroll
  for (int r = 0; r < 2; ++r)
    #pragma unroll
    for (int c = 0; c < 6; ++c)
      #pragma unroll
      for (int k = 0; k < 2; ++k){ accM[r][c][k] = 0.f; accC[r][c][k] = 0.f; }

  float4 xr[3], wr[3];

  auto loadX = [&](int c0){
    #pragma unroll
    for (int n = 0; n < 3; ++n){
      int item = tid + 256*n;          // 768 f4 items: ic(8) x row(4) x 24 f4
      int ic = item / 96, rem = item - ic*96;
      int r = rem / 24, c4 = rem - r*24;
      int row = y0 - 1 + r;
      float4 v = make_float4(0.f,0.f,0.f,0.f);
      if ((unsigned)row < 64u)
        v = *reinterpret_cast<const float4*>(X + (c0+ic)*HW + row*WW + c4*4);
      xr[n] = v;
    }
  };
  auto loadW = [&](int ch){
    #pragma unroll
    for (int n = 0; n < 3; ++n){
      int item = tid + 256*n;          // 576 f4 items: ocl(32) x 18 f4
      if (item < 576){
        int ocl = item / 18, j4 = item - ocl*18;
        wr[n] = *reinterpret_cast<const float4*>(Wt + (oc0+ocl)*4608 + ch*72 + j4*4);
      }
    }
  };
  auto storeXW = [&](){
    #pragma unroll
    for (int n = 0; n < 3; ++n){
      int item = tid + 256*n;
      int ic = item / 96, rem = item - ic*96;
      int r = rem / 24, c4 = rem - r*24;
      int row = y0 - 1 + r;
      if ((unsigned)row < 64u){
        float* dst = Xs + ic*416 + r*104 + 5 + c4*4;
        dst[0] = xr[n].x; dst[1] = xr[n].y; dst[2] = xr[n].z; dst[3] = xr[n].w;
      }
    }
    #pragma unroll
    for (int n = 0; n < 3; ++n){
      int item = tid + 256*n;
      if (item < 576){
        int ocl = item / 18, j4 = item - ocl*18;
        float v[4] = {wr[n].x, wr[n].y, wr[n].z, wr[n].w};
        #pragma unroll
        for (int l = 0; l < 4; ++l){
          int j = j4*4 + l;            // 0..71
          int g = j / 9, u = j - g*9;
          Wl[ocl*100 + g*12 + u] = v[l];
        }
      }
    }
  };

  loadX(0); loadW(0);
  for (int ch = 0; ch < 64; ++ch){
    __syncthreads();
    storeXW();
    __syncthreads();
    if (ch < 63){ loadX((ch+1)*8); loadW(ch+1); }
    #pragma unroll
    for (int p = 0; p < 4; ++p){
      #pragma unroll
      for (int i = 0; i < 2; ++i){
        const int g = 2*p + i;         // local ic 0..7, ascending
        float xv[4][8];
        #pragma unroll
        for (int r = 0; r < 4; ++r){
          const float2* xp = reinterpret_cast<const float2*>(Xs + g*416 + r*104 + xs + 4);
          float2 a0 = xp[0], a1 = xp[1], a2 = xp[2], a3 = xp[3];
          xv[r][0]=a0.x; xv[r][1]=a0.y; xv[r][2]=a1.x; xv[r][3]=a1.y;
          xv[r][4]=a2.x; xv[r][5]=a2.y; xv[r][6]=a3.x; xv[r][7]=a3.y;
        }
        #pragma unroll
        for (int ko = 0; ko < 2; ++ko){
          const float* wb = Wl + (ot + 16*ko)*100 + g*12;
          float4 w03 = *reinterpret_cast<const float4*>(wb);
          float4 w47 = *reinterpret_cast<const float4*>(wb + 4);
          float w8 = wb[8];
          float wv[9] = {w03.x,w03.y,w03.z,w03.w,w47.x,w47.y,w47.z,w47.w,w8};
          #pragma unroll
          for (int dy = 0; dy < 3; ++dy){
            #pragma unroll
            for (int dx = 0; dx < 3; ++dx){
              float w = wv[dy*3+dx];
              #pragma unroll
              for (int r = 0; r < 2; ++r)
                #pragma unroll
                for (int c = 0; c < 6; ++c)
                  accC[r][c][ko] += xv[r+dy][c+dx] * w;
            }
          }
        }
      }
    }
    // two-level fold per 8-ic chunk (identical order to R1-R3)
    #pragma unroll
    for (int r = 0; r < 2; ++r)
      #pragma unroll
      for (int c = 0; c < 6; ++c)
        #pragma unroll
        for (int k = 0; k < 2; ++k){ accM[r][c][k] += accC[r][c][k]; accC[r][c][k] = 0.f; }
  }
  #pragma unroll
  for (int ko = 0; ko < 2; ++ko){
    int oc = oc0 + ot + 16*ko;
    float b = Bc[oc];
    #pragma unroll
    for (int r = 0; r < 2; ++r){
      float v0 = fmaxf(accM[r][0][ko] + b, 0.f);
      float v1 = fmaxf(accM[r][1][ko] + b, 0.f);
      float v2 = fmaxf(accM[r][2][ko] + b, 0.f);
      float v3 = fmaxf(accM[r][3][ko] + b, 0.f);
      float v4 = fmaxf(accM[r][4][ko] + b, 0.f);
      float v5 = fmaxf(accM[r][5][ko] + b, 0.f);
      float2* yp = reinterpret_cast<float2*>(Y + oc*HW + (y0+r)*WW + xs);
      yp[0] = make_float2(v0, v1);
      yp[1] = make_float2(v2, v3);
      yp[2] = make_float2(v4, v5);
    }
  }
}

// ---------------- K2: 1x1 heads + softmax + box decode (+ hist) ----------------
__device__ __forceinline__ u32 sortkey(float s){
  u32 u = __float_as_uint(s);
  return u ^ ((u & 0x80000000u) ? 0xFFFFFFFFu : 0x80000000u);
}

__global__ __launch_bounds__(256) void k_head(
    const float* __restrict__ Y, const float* __restrict__ cw,
    const float* __restrict__ cb, const float* __restrict__ bw,
    const float* __restrict__ bb, const float* __restrict__ info,
    float* __restrict__ scores, float4* __restrict__ boxes, u32* __restrict__ hist)
{
  __shared__ float Ys[4096];
  __shared__ float Wsh[4096];
  const int tid = threadIdx.x;
  const int p0  = blockIdx.x * 64;
  const int po  = tid & 15;
  const int oj  = tid >> 4;
  float accM[4][4], accC[4][4];
  #pragma unroll
  for (int p = 0; p < 4; ++p)
    #pragma unroll
    for (int k = 0; k < 4; ++k){ accM[p][k] = 0.f; accC[p][k] = 0.f; }

  for (int c0 = 0; c0 < CC; c0 += 64){
    __syncthreads();
    for (int i = tid; i < 4096; i += 256){
      int c = i >> 6, p = i & 63;
      Ys[i] = Y[(c0 + c) * HW + p0 + p];
    }
    for (int i = tid; i < 4096; i += 256){
      int c = i >> 6, o = i & 63;
      int gc = c0 + c;
      float v = 0.f;
      if (o < 18) v = cw[o * 512 + gc];
      else if (o < 54) v = bw[(o - 18) * 512 + gc];
      Wsh[i] = v;
    }
    __syncthreads();
    for (int c = 0; c < 64; ++c){
      const float4 xv = *reinterpret_cast<const float4*>(Ys + c*64 + po*4);
      float xa[4] = {xv.x, xv.y, xv.z, xv.w};
      const float* wrd = Wsh + c*64 + oj;
      float wv[4] = {wrd[0], wrd[16], wrd[32], wrd[48]};
      #pragma unroll
      for (int p = 0; p < 4; ++p)
        #pragma unroll
        for (int k = 0; k < 4; ++k)
          accC[p][k] += xa[p] * wv[k];
    }
    #pragma unroll
    for (int p = 0; p < 4; ++p)
      #pragma unroll
      for (int k = 0; k < 4; ++k){ accM[p][k] += accC[p][k]; accC[p][k] = 0.f; }
  }
  __syncthreads();
  #pragma unroll
  for (int p = 0; p < 4; ++p)
    #pragma unroll
    for (int k = 0; k < 4; ++k){
      int o = oj + 16*k;
      float bias = (o < 18) ? cb[o] : ((o < 54) ? bb[o - 18] : 0.f);
      Ys[(po*4 + p)*64 + o] = accM[p][k] + bias;
    }
  __syncthreads();
  float imH = info[0], imW = info[1], imS = info[2];
  for (int it = tid; it < 576; it += 256){
    int pl = it / 9;
    int a  = it - pl*9;
    const float* L = Ys + pl*64;
    float l0 = L[a], l1 = L[9 + a];
    float mx = fmaxf(l0, l1);
    float e0 = expf(l0 - mx), e1 = expf(l1 - mx);
    float sc = e1 / (e0 + e1);
    float d0 = L[18 + a*4 + 0], d1 = L[18 + a*4 + 1];
    float d2 = L[18 + a*4 + 2], d3 = L[18 + a*4 + 3];
    int pos = p0 + pl;
    int yy = pos / 96;
    int xx = pos - yy * 96;
    float aw = c_aw[a], ah = c_ah[a];
    float acx = (float)(xx * 16 + 8);
    float acy = (float)(yy * 16 + 8);
    float cx = __fadd_rn(__fmul_rn(d0, aw), acx);
    float cy = __fadd_rn(__fmul_rn(d1, ah), acy);
    float pw = __fmul_rn(expf(d2), aw);
    float ph = __fmul_rn(expf(d3), ah);
    float hx = __fmul_rn(0.5f, pw);
    float hy = __fmul_rn(0.5f, ph);
    float x1 = fminf(fmaxf(__fadd_rn(cx, -hx), 0.f), imW - 1.f);
    float y1 = fminf(fmaxf(__fadd_rn(cy, -hy), 0.f), imH - 1.f);
    float x2 = fminf(fmaxf(__fadd_rn(cx,  hx), 0.f), imW - 1.f);
    float y2 = fminf(fmaxf(__fadd_rn(cy,  hy), 0.f), imH - 1.f);
    float ms = 16.f * imS;
    bool keep = ((x2 - x1 + 1.f) >= ms) && ((y2 - y1 + 1.f) >= ms);
    int g = pos * 9 + a;
    float val = keep ? sc : -__builtin_inff();
    scores[g] = val;
    boxes[g]  = make_float4(x1, y1, x2, y2);
    atomicAdd(&hist[sortkey(val) >> 16], 1u);
  }
}

// ---------------- top-6000 selection ----------------
__global__ __launch_bounds__(1024) void k_thresh1(const u32* __restrict__ hist, u32* __restrict__ ctr){
  __shared__ u32 cs[1024];
  int t = threadIdx.x;
  int b0 = t * 64;
  u32 s = 0;
  for (int i = 0; i < 64; ++i) s += hist[b0 + i];
  cs[t] = s;
  __syncthreads();
  for (int off = 1; off < 1024; off <<= 1){
    u32 v = cs[t];
    u32 ad = (t + off < 1024) ? cs[t + off] : 0u;
    __syncthreads();
    cs[t] = v + ad;
    __syncthreads();
  }
  u32 here  = cs[t];
  u32 after = (t < 1023) ? cs[t + 1] : 0u;
  if (here >= 6000u && after < 6000u){
    u32 acc = after;
    for (int b = b0 + 63; b >= b0; --b){
      u32 h = hist[b];
      acc += h;
      if (acc >= 6000u){ ctr[1] = (u32)b; ctr[2] = acc - h; break; }
    }
  }
  if (t == 0 && cs[0] < 6000u){ ctr[1] = 0u; ctr[2] = 0u; }
}

__global__ __launch_bounds__(256) void k_hist2(const float* __restrict__ scores,
                                               const u32* __restrict__ ctr, u32* __restrict__ hist2){
  int i = blockIdx.x * 256 + threadIdx.x;
  if (i >= NANCH) return;
  u32 key = sortkey(scores[i]);
  if ((key >> 16) == ctr[1]) atomicAdd(&hist2[key & 0xFFFFu], 1u);
}

__global__ __launch_bounds__(1024) void k_thresh2(const u32* __restrict__ hist2, u32* __restrict__ ctr){
  __shared__ u32 cs[1024];
  int t = threadIdx.x;
  u32 above  = ctr[2];
  u32 target = 6000u - above;
  int b0 = t * 64;
  u32 s = 0;
  for (int i = 0; i < 64; ++i) s += hist2[b0 + i];
  cs[t] = s;
  __syncthreads();
  for (int off = 1; off < 1024; off <<= 1){
    u32 v = cs[t];
    u32 ad = (t + off < 1024) ? cs[t + off] : 0u;
    __syncthreads();
    cs[t] = v + ad;
    __syncthreads();
  }
  u32 here  = cs[t];
  u32 after = (t < 1023) ? cs[t + 1] : 0u;
  if (here >= target && after < target){
    u32 acc = after;
    for (int b = b0 + 63; b >= b0; --b){
      u32 h = hist2[b];
      acc += h;
      if (acc >= target){ ctr[3] = (ctr[1] << 16) | (u32)b; break; }
    }
  }
  if (t == 0 && cs[0] < target) ctr[3] = (ctr[1] << 16);
  if (t == 0) ctr[4] = 6000u;
}

__global__ __launch_bounds__(256) void k_compact(const float* __restrict__ scores,
                                                 u32* __restrict__ ctr, u64* __restrict__ keys){
  int i = blockIdx.x * 256 + threadIdx.x;
  if (i >= NANCH) return;
  u32 key = sortkey(scores[i]);
  if (key >= ctr[3]){
    u32 pos = atomicAdd(&ctr[0], 1u);
    if (pos < CAP) keys[pos] = ((u64)key << 32) | (u64)(u32)(~(u32)i);
  }
}

// ---------------- K-rank: exact rank by enumeration, scatter topB/topA ----------------
// keys unique (embedded ~idx) -> rank(i) = #{j: key_j > key_i} is a permutation.
// Replaces the single-CU 91-stage bitonic sort with a full-GPU O(N^2/P) pass.
__global__ __launch_bounds__(256) void k_rank(const u64* __restrict__ keys, u32* __restrict__ ctr,
                                              const float4* __restrict__ boxes,
                                              float4* __restrict__ topB, float* __restrict__ topA){
  __shared__ u64 ks[2048];   // 16 KB
  const int t  = threadIdx.x;
  const int gi = blockIdx.x * 256 + t;
  u32 count = ctr[0]; if (count > CAP) count = CAP;
  u64 my = (gi < (int)count) ? keys[gi] : 0ull;
  int rank = 0;
  for (int c0 = 0; c0 < CAP; c0 += 2048){
    __syncthreads();
    for (int s = t; s < 2048; s += 256){
      int j = c0 + s;
      ks[s] = (j < (int)count) ? keys[j] : 0ull;
    }
    __syncthreads();
    if (gi < (int)count){
      const ulonglong2* kp = reinterpret_cast<const ulonglong2*>(ks);
      #pragma unroll 8
      for (int s = 0; s < 1024; ++s){
        ulonglong2 kv = kp[s];
        rank += (kv.x > my) + (kv.y > my);
      }
    }
  }
  if (gi < (int)count && rank < PRE){
    if (!((my >> 32) & 0x80000000ull))
      atomicMin((int*)(ctr + 4), rank);        // first non-finite rank
    u32 idx = ~(u32)my;
    float4 bv = make_float4(0.f,0.f,0.f,0.f);
    float area = 1.f;
    if (idx < NANCH){
      bv = boxes[idx];
      area = (bv.z - bv.x + 1.f) * (bv.w - bv.y + 1.f);
    }
    topB[rank] = bv;
    topA[rank] = area;
  }
}

// ---------------- NMS stage A: suppression bit-matrix M[6000][188] ----------------
__global__ __launch_bounds__(256) void k_iou(const float4* __restrict__ topB, const float* __restrict__ topA,
                                             u32* __restrict__ M){
  __shared__ float4 jb[3072];   // 48 KB
  const int tid = threadIdx.x;
  const int rr  = tid & 31;
  const int wg  = tid >> 5;
  const int i   = blockIdx.x * 32 + rr;
  float4 bi = make_float4(0.f,0.f,0.f,0.f); float ai = 1.f;
  if (i < PRE){ bi = topB[i]; ai = topA[i]; }
  for (int ph = 0; ph < 2; ++ph){
    __syncthreads();
    for (int s = tid; s < 3072; s += 256){
      int j = ph*3072 + s;
      jb[s] = (j < PRE) ? topB[j] : make_float4(0.f,0.f,0.f,0.f);
    }
    __syncthreads();
    if (i >= PRE) continue;
    int nw = (ph == 0) ? 96 : 92;
    #pragma unroll
    for (int m = 0; m < 12; ++m){
      int wl = wg + 8*m;
      if (wl >= nw) continue;
      int w = ph*96 + wl;
      int jbase = w * 32;
      if (jbase + 31 <= i){ M[(size_t)i*188 + w] = 0u; continue; }
      u32 bits = 0u;
      for (int s = 0; s < 32; ++s){
        int j = jbase + s;
        if (j <= i || j >= PRE) continue;
        float4 bj = jb[j - ph*3072];
        float aj = (bj.z - bj.x + 1.f) * (bj.w - bj.y + 1.f);
        float xx1 = fmaxf(bi.x, bj.x);
        float yy1 = fmaxf(bi.y, bj.y);
        float xx2 = fminf(bi.z, bj.z);
        float yy2 = fminf(bi.w, bj.w);
        float iw = fmaxf(xx2 - xx1 + 1.f, 0.f);
        float ih = fmaxf(yy2 - yy1 + 1.f, 0.f);
        float inter = iw * ih;
        float iou = inter / (ai + aj - inter);
        if (iou > 0.7f) bits |= (1u << s);
      }
      M[(size_t)i*188 + w] = bits;
    }
  }
}

// ---------------- NMS stage B: single-wave register-resident greedy scan ----------------
__global__ __launch_bounds__(64) void k_reduce(const u32* __restrict__ M, const float4* __restrict__ topB,
                                               const u32* __restrict__ ctr, float* __restrict__ out){
  __shared__ int kept[POST];
  const int t = threadIdx.x;
  int validN = (int)ctr[0];
  int finN   = (int)ctr[4];
  if (finN < validN) validN = finN;
  if (validN > PRE)  validN = PRE;
  auto initw = [&](int w)->u32{
    if (w >= 188) return 0xFFFFFFFFu;
    int lo = w * 32;
    if (lo + 32 <= validN) return 0u;
    if (lo >= validN) return 0xFFFFFFFFu;
    return ~((1u << (validN - lo)) - 1u);
  };
  u32 s0 = initw(t), s1 = initw(64 + t), s2 = initw(128 + t);
  for (int k = 0; k < POST; ++k){
    int i = -1;
    u64 b0 = __ballot(s0 != 0xFFFFFFFFu);
    if (b0){
      int L = (int)__ffsll((unsigned long long)b0) - 1;
      u32 v = (u32)__shfl((int)s0, L, 64);
      i = L*32 + (__ffs((int)(~v)) - 1);
    } else {
      u64 b1 = __ballot(s1 != 0xFFFFFFFFu);
      if (b1){
        int L = (int)__ffsll((unsigned long long)b1) - 1;
        u32 v = (u32)__shfl((int)s1, L, 64);
        i = 2048 + L*32 + (__ffs((int)(~v)) - 1);
      } else {
        u64 b2 = __ballot(s2 != 0xFFFFFFFFu);
        if (b2){
          int L = (int)__ffsll((unsigned long long)b2) - 1;
          u32 v = (u32)__shfl((int)s2, L, 64);
          i = 4096 + L*32 + (__ffs((int)(~v)) - 1);
        }
      }
    }
    if (t == 0) kept[k] = i;
    if (i >= 0){
      const u32* row = M + (size_t)i * 188;
      u32 r0 = row[t];
      u32 r1 = (64 + t < 188) ? row[64 + t] : 0u;
      u32 r2 = (128 + t < 188) ? row[128 + t] : 0u;
      s0 |= r0; s1 |= r1; s2 |= r2;
      int iw = i >> 5, ib = i & 31;
      if (iw == t) s0 |= (1u << ib);
      else if (iw == 64 + t) s1 |= (1u << ib);
      else if (iw == 128 + t) s2 |= (1u << ib);
    }
  }
  __syncthreads();
  for (int q = t; q < 1500; q += 64){
    int r = q / 5, c = q - r*5;
    int i = kept[r];
    float v = 0.f;
    if (i >= 0 && c > 0){
      float4 bx = topB[i];
      v = (c == 1) ? bx.x : (c == 2) ? bx.y : (c == 3) ? bx.z : bx.w;
    }
    out[q] = v;
  }
}

// ---------------- launch ----------------
extern "C" void kernel_launch(void* const* d_in, const int* in_sizes, int n_in,
                              void* d_out, int out_size, void* d_ws, size_t ws_size,
                              hipStream_t stream)
{
  const float* fm   = (const float*)d_in[0];
  const float* info = (const float*)d_in[1];
  const float* cw3  = (const float*)d_in[2];
  const float* cb3  = (const float*)d_in[3];
  const float* clw  = (const float*)d_in[4];
  const float* clb  = (const float*)d_in[5];
  const float* bbw  = (const float*)d_in[6];
  const float* bbb  = (const float*)d_in[7];
  float* out = (float*)d_out;

  char* base = (char*)d_ws;
  u32*   hist   = (u32*)  (base + 0);          // 65536 u32
  u32*   hist2  = (u32*)  (base + 262144);     // 65536 u32
  u32*   ctr    = (u32*)  (base + 524288);     // [0]=count [1]=T16 [2]=above [3]=K32 [4]=finiteN
  float* Y      = (float*)(base + 524544);     // 512*6144 f32 = 12.58 MB
  u32*   M      = (u32*)  (base + 524544);     // overlays Y (dead after k_head): 4.5 MB
  float* scores = (float*)(base + 13107456);   // 55296 f32
  float4* boxes = (float4*)(base + 13328640);  // 55296 f32x4
  u64*   keys   = (u64*)  (base + 14213376);   // 8192 u64
  float4* topB  = (float4*)(base + 14278912);  // 6016 f32x4
  float* topA   = (float*)(base + 14375168);   // 6016 f32
  // total ws use: 14399232 B (~14.4 MB)

  hipMemsetAsync(base, 0, 524544, stream);     // hist, hist2, ctr
  k_conv3  <<<dim3(32, 16), 256, 0, stream>>>(fm, cw3, cb3, Y);
  k_head   <<<96,  256, 0, stream>>>(Y, clw, clb, bbw, bbb, info, scores, boxes, hist);
  k_thresh1<<<1,  1024, 0, stream>>>(hist, ctr);
  k_hist2  <<<216, 256, 0, stream>>>(scores, ctr, hist2);
  k_thresh2<<<1,  1024, 0, stream>>>(hist2, ctr);
  k_compact<<<216, 256, 0, stream>>>(scores, ctr, keys);
  k_rank   <<<32,  256, 0, stream>>>(keys, ctr, boxes, topB, topA);
  k_iou    <<<188, 256, 0, stream>>>(topB, topA, M);
  k_reduce <<<1,    64, 0, stream>>>(M, topB, ctr, out);
}